// Round 15
// baseline (427.511 us; speedup 1.0000x reference)
//
#include <hip/hip_runtime.h>
#include <math.h>
#include <float.h>

// Problem constants (B=32, C=32, H=W=32, V=4096)
#define BS    32
#define CH    32
#define HH    32
#define VV    4096
#define FELEMS (BS*CH*HH*HH)   // 1048576
#define NROWS_TOTAL 43680      // sum over scales of B*pn*pn

typedef unsigned short ushort_t;
typedef unsigned long long u64_t;
typedef _Float16 half_t;
typedef __attribute__((ext_vector_type(8))) _Float16 half8;
typedef __attribute__((ext_vector_type(4))) float floatx4;

// 2-way fp16 split: x ~= h + l, residual <= 2^-22 |x|
__device__ inline void split2(float x, half_t* h, half_t* l) {
    half_t hh = (half_t)x;
    float r = x - (float)hh;
    *h = hh;
    *l = (half_t)r;
}

// fp32 -> sortable-descending key32 (bigger score => smaller key)
__device__ inline unsigned score_key32(float s) {
    unsigned u = __builtin_bit_cast(unsigned, s);
    unsigned m = (u & 0x80000000u) ? ~u : (u | 0x80000000u);  // monotone asc
    return ~m;                                                 // desc
}

// ---------------------------------------------------------------------------
// prep (grid 1024x256): emb fp16-split + nesqh, zero f_hat output, zero
// hits/lacc, init pk keys to +inf. Replaces the d_out memset.
__global__ __launch_bounds__(256) void prep_kernel(const float* __restrict__ emb,
                                                   half_t* __restrict__ ehi,
                                                   half_t* __restrict__ elo,
                                                   float* __restrict__ nesqh,
                                                   float* __restrict__ wszero,
                                                   u64_t* __restrict__ pk,
                                                   float* __restrict__ dout) {
    int gid = blockIdx.x * 256 + threadIdx.x;      // 262144 threads
    float4 z4 = {0.f, 0.f, 0.f, 0.f};
    *(float4*)(dout + (size_t)gid * 4) = z4;
    if (gid < 8448) wszero[gid] = 0.f;             // hits + pad + lacc
    if (gid < NROWS_TOTAL) pk[gid] = ~0ull;        // +inf keys
    if (gid < VV) {
        int v = gid;
        const float* ep = emb + (size_t)v * CH;
        float s = 0.f;
        half_t h[CH], l[CH];
#pragma unroll
        for (int i = 0; i < CH; i++) {
            float e = ep[i];
            s = fmaf(e, e, s);
            split2(e, &h[i], &l[i]);
        }
        nesqh[v] = -0.5f * s;
#pragma unroll
        for (int q = 0; q < 4; q++) {
            half8 H, L;
#pragma unroll
            for (int k = 0; k < 8; k++) {
                H[k] = h[q * 8 + k];
                L[k] = l[q * 8 + k];
            }
            *(half8*)(ehi + (size_t)v * CH + q * 8) = H;
            *(half8*)(elo + (size_t)v * CH + q * 8) = L;
        }
    }
}

// ---------------------------------------------------------------------------
// mean-pool, pn = 8/16: thread per (n,c); n=(b*pn+i)*pn+j
__global__ __launch_bounds__(256) void pool_kernel(const float* __restrict__ f,
                                                   half_t* __restrict__ zhi,
                                                   half_t* __restrict__ zlo, int pn) {
    int tid = blockIdx.x * 256 + threadIdx.x;
    int c = tid % CH;
    int n = tid / CH;
    if (n >= BS * pn * pn) return;
    int j = n % pn, i = (n / pn) % pn, b = n / (pn * pn);
    int ps = HH / pn;
    const float* base = f + (((size_t)(b * CH + c) * HH) + i * ps) * HH + j * ps;
    float s = 0.f;
    for (int dy = 0; dy < ps; dy++)
        for (int dx = 0; dx < ps; dx++)
            s += base[dy * HH + dx];
    s *= (1.0f / (ps * ps));
    split2(s, &zhi[tid], &zlo[tid]);
}

// mean-pool, pn = 1/2: block per (n,c) pair; SQ also accumulates sumsq (si=0).
template <bool SQ>
__global__ __launch_bounds__(256) void pool_big_kernel(const float* __restrict__ f,
                                                       half_t* __restrict__ zhi,
                                                       half_t* __restrict__ zlo,
                                                       float* __restrict__ lacc, int pn) {
    int pair = blockIdx.x;            // pair = n*CH + c
    int c = pair & 31;
    int n = pair >> 5;
    int j = n % pn, i = (n / pn) % pn, b = n / (pn * pn);
    int ps = HH / pn;                 // 32 or 16
    int npx = ps * ps;
    const float* base = f + (((size_t)(b * CH + c) * HH) + i * ps) * HH + j * ps;
    float s = 0.f, s2 = 0.f;
    for (int p = threadIdx.x; p < npx; p += 256) {
        float v = base[(p / ps) * HH + (p % ps)];
        s += v;
        if (SQ) s2 = fmaf(v, v, s2);
    }
    __shared__ float sh[256];
    sh[threadIdx.x] = s;
    __syncthreads();
    for (int o = 128; o > 0; o >>= 1) {
        if (threadIdx.x < o) sh[threadIdx.x] += sh[threadIdx.x + o];
        __syncthreads();
    }
    if (threadIdx.x == 0) {
        float t = sh[0] * (1.0f / npx);
        int o = n * CH + c;
        split2(t, &zhi[o], &zlo[o]);
    }
    if (SQ) {
        __syncthreads();
        sh[threadIdx.x] = s2;
        __syncthreads();
        for (int o = 128; o > 0; o >>= 1) {
            if (threadIdx.x < o) sh[threadIdx.x] += sh[threadIdx.x + o];
            __syncthreads();
        }
        if (threadIdx.x == 0) atomicAdd(lacc, sh[0]);
    }
}

// mean-pool, pn = 4 (ps=8, 64 px): wave per (n,c) pair, shuffle reduce
__global__ __launch_bounds__(256) void pool_wave_kernel(const float* __restrict__ f,
                                                        half_t* __restrict__ zhi,
                                                        half_t* __restrict__ zlo) {
    const int pn = 4, ps = 8;
    int lane = threadIdx.x & 63;
    int pair = blockIdx.x * 4 + (threadIdx.x >> 6);
    int c = pair & 31;
    int n = pair >> 5;
    int j = n % pn, i = (n / pn) % pn, b = n / (pn * pn);
    const float* base = f + (((size_t)(b * CH + c) * HH) + i * ps) * HH + j * ps;
    float s = base[(lane >> 3) * HH + (lane & 7)];
#pragma unroll
    for (int m = 1; m < 64; m <<= 1) s += __shfl_xor(s, m, 64);
    if (lane == 0) {
        float t = s * (1.0f / 64.0f);
        int o = n * CH + c;
        split2(t, &zhi[o], &zlo[o]);
    }
}

// ---------------------------------------------------------------------------
// 3-MFMA fp16 score chain for one 16-row group vs one 16-code tile
// score = z.e - 0.5|e|^2 = ah.bh + ah.bl + al.bh  (al.bl <= 2^-22 dropped)
__device__ inline floatx4 score_chain(half8 ah, half8 al,
                                      half8 bh, half8 bl, floatx4 ehv) {
    floatx4 acc;
    acc = __builtin_amdgcn_mfma_f32_16x16x32_f16(ah, bh, ehv, 0, 0, 0);
    acc = __builtin_amdgcn_mfma_f32_16x16x32_f16(ah, bl, acc, 0, 0, 0);
    acc = __builtin_amdgcn_mfma_f32_16x16x32_f16(al, bh, acc, 0, 0, 0);
    return acc;
}

__device__ inline void sel4(const floatx4& acc, int v, float* best, int* bidx) {
#pragma unroll
    for (int r = 0; r < 4; r++) {
        // strict >: lane-local scan is increasing v -> keeps lowest v on tie
        if (acc[r] > best[r]) { best[r] = acc[r]; bidx[r] = v; }
    }
}

// argmin core. Wave wv scans TPW v-tiles from t0+wv*TPW over RT 16-row tiles.
// 2-deep rotating prefetch (A/B buffers, unroll-by-2): tile t's emb loads
// issue ~2 tiles (~300 cyc) ahead of use -> L2 latency hidden even at the
// grid-limited 4 waves/SIMD. Deferred-select interleave (RT>=2). Winner per
// row merged cross-block via packed-key atomicMin (max score, lowest idx on
// tie == jnp.argmin). Consumption order unchanged -> winners bit-identical.
template <int RT, int TPW>
__device__ inline void argmin_body(const half8* a1, const half8* a2,
                                   const half_t* __restrict__ ehi,
                                   const half_t* __restrict__ elo,
                                   const float* __restrict__ nesqh,
                                   u64_t* __restrict__ pk, int row0, int t0) {
    static_assert(TPW % 2 == 0, "TPW must be even for the 2-deep pipeline");
    const int tid  = threadIdx.x;
    const int wv   = tid >> 6;
    const int lane = tid & 63;
    const int col  = lane & 15;
    const int quad = lane >> 4;

    float best[RT][4];
    int   bidx[RT][4];
#pragma unroll
    for (int rt = 0; rt < RT; rt++)
#pragma unroll
        for (int r = 0; r < 4; r++) { best[rt][r] = -FLT_MAX; bidx[rt][r] = 0; }

    int t = t0 + wv * TPW;
    const int tend = t + TPW;

    // prefetch tiles t (A) and t+1 (B)
    size_t ea = ((size_t)((t << 4) + col) << 5) + (quad << 3);
    half8 pa1 = *(const half8*)(ehi + ea);
    half8 pa2 = *(const half8*)(elo + ea);
    float pae = nesqh[(t << 4) + col];
    size_t eb = ((size_t)(((t + 1) << 4) + col) << 5) + (quad << 3);
    half8 pb1 = *(const half8*)(ehi + eb);
    half8 pb2 = *(const half8*)(elo + eb);
    float pbe = nesqh[((t + 1) << 4) + col];

    floatx4 acc[RT];
    int vprev = 0;
    if (RT > 1) acc[RT - 1] = floatx4{-FLT_MAX, -FLT_MAX, -FLT_MAX, -FLT_MAX};

    auto consume = [&](half8 b1, half8 b2, float eh, int vcur) {
        const floatx4 ehv = {eh, eh, eh, eh};
        if (RT == 1) {
            acc[0] = score_chain(a1[0], a2[0], b1, b2, ehv);
            sel4(acc[0], vcur, best[0], bidx[0]);
        } else {
            acc[0] = score_chain(a1[0], a2[0], b1, b2, ehv);
            sel4(acc[RT - 1], vprev, best[RT - 1], bidx[RT - 1]);  // deferred
#pragma unroll
            for (int rt = 1; rt < RT; rt++) {
                acc[rt] = score_chain(a1[rt], a2[rt], b1, b2, ehv);
                sel4(acc[rt - 1], vcur, best[rt - 1], bidx[rt - 1]);
            }
            vprev = vcur;
        }
    };

    for (; t < tend; t += 2) {
        {   // even tile t: consume A, prefetch t+2 into A
            const half8 cb1 = pa1, cb2 = pa2;
            const float ce = pae;
            const int tn = (t + 2 < tend) ? (t + 2) : t;
            const size_t e2 = ((size_t)((tn << 4) + col) << 5) + (quad << 3);
            pa1 = *(const half8*)(ehi + e2);
            pa2 = *(const half8*)(elo + e2);
            pae = nesqh[(tn << 4) + col];
            consume(cb1, cb2, ce, (t << 4) + col);
        }
        {   // odd tile t+1: consume B, prefetch t+3 into B
            const half8 cb1 = pb1, cb2 = pb2;
            const float ce = pbe;
            const int tn = (t + 3 < tend) ? (t + 3) : (t + 1);
            const size_t e2 = ((size_t)((tn << 4) + col) << 5) + (quad << 3);
            pb1 = *(const half8*)(ehi + e2);
            pb2 = *(const half8*)(elo + e2);
            pbe = nesqh[(tn << 4) + col];
            consume(cb1, cb2, ce, ((t + 1) << 4) + col);
        }
    }
    if (RT > 1) sel4(acc[RT - 1], vprev, best[RT - 1], bidx[RT - 1]);

    // reduce across the 16 cols (v within tile) of each quad group
#pragma unroll
    for (int m = 1; m < 16; m <<= 1) {
#pragma unroll
        for (int rt = 0; rt < RT; rt++)
#pragma unroll
            for (int r = 0; r < 4; r++) {
                float s2 = __shfl_xor(best[rt][r], m, 64);
                int   v2 = __shfl_xor(bidx[rt][r], m, 64);
                if (s2 > best[rt][r] ||
                    (s2 == best[rt][r] && v2 < bidx[rt][r])) {
                    best[rt][r] = s2; bidx[rt][r] = v2;
                }
            }
    }

    __shared__ float sbs[4 * RT * 16];
    __shared__ int   sbi[4 * RT * 16];
    if (col == 0) {
#pragma unroll
        for (int rt = 0; rt < RT; rt++)
#pragma unroll
            for (int r = 0; r < 4; r++) {
                int row = rt * 16 + (quad << 2) + r;
                sbs[wv * RT * 16 + row] = best[rt][r];
                sbi[wv * RT * 16 + row] = bidx[rt][r];
            }
    }
    __syncthreads();
    if (tid < RT * 16) {
        float s = sbs[tid];
        int   v = sbi[tid];
        for (int w = 1; w < 4; w++) {
            float s2 = sbs[w * RT * 16 + tid];
            int   v2 = sbi[w * RT * 16 + tid];
            if (s2 > s || (s2 == s && v2 < v)) { s = s2; v = v2; }
        }
        u64_t key = ((u64_t)score_key32(s) << 32) | (unsigned)v;
        atomicMin(pk + row0 + tid, key);
    }
}

// generic stage: z-splits from memory. grid = (nRowBlocks, VS)
template <int RT, int VS>
__global__ __launch_bounds__(256) void argmin_stage(const half_t* __restrict__ zhi,
                                                    const half_t* __restrict__ zlo,
                                                    const half_t* __restrict__ ehi,
                                                    const half_t* __restrict__ elo,
                                                    const float* __restrict__ nesqh,
                                                    u64_t* __restrict__ pk) {
    const int lane = threadIdx.x & 63;
    const int col  = lane & 15;
    const int quad = lane >> 4;
    const int row0 = blockIdx.x * (16 * RT);

    half8 a1[RT], a2[RT];
#pragma unroll
    for (int rt = 0; rt < RT; rt++) {
        size_t off = ((size_t)(row0 + rt * 16 + col) << 5) + (quad << 3);
        a1[rt] = *(const half8*)(zhi + off);
        a2[rt] = *(const half8*)(zlo + off);
    }
    argmin_body<RT, 64 / VS>(a1, a2, ehi, elo, nesqh, pk,
                             row0, (int)blockIdx.y * (256 / VS));
}

// si=5 fused: pool is identity (pn=32) -> split2 straight from frest.
// grid = (512, 2): RT=4, VS=2, each wave scans 32 tiles. (r10-proven config;
// VS=4 regressed: redundant split2 prologue outweighs occupancy.)
__global__ __launch_bounds__(256) void argmin5_fused(const float* __restrict__ frest,
                                                     const half_t* __restrict__ ehi,
                                                     const half_t* __restrict__ elo,
                                                     const float* __restrict__ nesqh,
                                                     u64_t* __restrict__ pk) {
    const int lane = threadIdx.x & 63;
    const int col  = lane & 15;
    const int quad = lane >> 4;
    const int row0 = blockIdx.x * 64;   // RT=4

    half8 a1[4], a2[4];
#pragma unroll
    for (int rt = 0; rt < 4; rt++) {
        int n = row0 + rt * 16 + col;               // row = (b*32+i)*32+j
        int b = n >> 10, i = (n >> 5) & 31, j = n & 31;
        const float* p = frest + ((((size_t)(b * CH + quad * 8)) * HH + i) * HH + j);
#pragma unroll
        for (int k = 0; k < 8; k++) {
            half_t h, l;
            split2(p[(size_t)k * (HH * HH)], &h, &l);   // c stride = 1024
            a1[rt][k] = h; a2[rt][k] = l;
        }
    }
    argmin_body<4, 32>(a1, a2, ehi, elo, nesqh, pk,
                       row0, (int)blockIdx.y * 128);
}

// ---------------------------------------------------------------------------
// bicubic weights, a=-0.75, half-pixel, edge clamp (matches ref _bicubic_mat)
__device__ inline void cubic_w(float xs, int pn, int* ix, float* w) {
    const float a = -0.75f;
    float xf = floorf(xs);
    int x0 = (int)xf;
    float t = xs - xf;
#pragma unroll
    for (int j = -1; j <= 2; j++) {
        float d = fabsf(t - (float)j);
        float ww;
        if (d < 1.0f)      ww = ((a + 2.0f) * d - (a + 3.0f)) * d * d + 1.0f;
        else if (d < 2.0f) ww = ((a * d - 5.0f * a) * d + 8.0f * a) * d - 4.0f * a;
        else               ww = 0.0f;
        int xi = x0 + j;
        xi = xi < 0 ? 0 : (xi > pn - 1 ? pn - 1 : xi);
        ix[j + 1] = xi;
        w[j + 1]  = ww;
    }
}

// Fused gather + bicubic upsample from packed keys (idx = low 32 bits).
// Thread mapping [b][c][Y][X], X minor -> coalesced hup writes; scattered
// emb gathers absorbed by L1/L2 (emb = 512 KB). (r5-verified layout.)
__global__ __launch_bounds__(256) void upsample_gather_kernel(const u64_t* __restrict__ pk,
                                                              const float* __restrict__ emb,
                                                              float* __restrict__ hu, int pn) {
    int tid = blockIdx.x * 256 + threadIdx.x;   // [b][c][Y][X]
    int X = tid & 31;
    int Y = (tid >> 5) & 31;
    int c = (tid >> 10) & 31;
    int b = tid >> 15;
    float scale = (float)pn / (float)HH;
    int iy[4], ix[4];
    float wy[4], wx[4];
    cubic_w(((float)Y + 0.5f) * scale - 0.5f, pn, iy, wy);
    cubic_w(((float)X + 0.5f) * scale - 0.5f, pn, ix, wx);
    const u64_t* ib = pk + b * pn * pn;
    float s = 0.f;
#pragma unroll
    for (int a = 0; a < 4; a++) {
        float rsum = 0.f;
#pragma unroll
        for (int b2 = 0; b2 < 4; b2++) {
            int idx = (int)(unsigned)(ib[iy[a] * pn + ix[b2]] & 0xFFFFFFFFull);
            rsum = fmaf(emb[(size_t)idx * CH + c], wx[b2], rsum);
        }
        s = fmaf(rsum, wy[a], s);
    }
    hu[tid] = s;
}

// ---------------------------------------------------------------------------
// Phi + residual: dst = src - (0.5*h + 0.5*(conv3x3(h)+bias))
// grid: b(32) x yt(8) x co-quarter(4) = 1024 blocks (4 blocks/CU);
// block 256 = tx(32) x ty(8); thread: 4 rows x col tx x 1 co (co = coq*8+ty).
// (r9/r10-proven shape. r11's 2-row variant blew VGPR to 180 — keep as-is.)
__global__ __launch_bounds__(256) void conv_phi_kernel(const float* __restrict__ hin,
                                                       const float* __restrict__ w,
                                                       const float* __restrict__ bias,
                                                       const float* __restrict__ src,
                                                       float* __restrict__ dst) {
    const int coq = blockIdx.x & 3;
    const int yt  = (blockIdx.x >> 2) & 7;
    const int b   = blockIdx.x >> 5;
    const int tx  = threadIdx.x & 31;
    const int ty  = threadIdx.x >> 5;     // 0..7
    const int y0  = yt * 4;

    __shared__ float wl[8 * 32 * 12];     // 12 KB
    __shared__ float til[16 * 6 * 34];    // 13.1 KB

    {
        const float* wsrc = w + (size_t)coq * 8 * CH * 9;
        for (int i = threadIdx.x; i < 8 * 32 * 12; i += 256) {
            int k = i % 12;
            wl[i] = (k < 9) ? wsrc[(i / 12) * 9 + k] : 0.f;
        }
    }

    const int co = coq * 8 + ty;
    float acc[4];
#pragma unroll
    for (int ry = 0; ry < 4; ry++) acc[ry] = bias[co];

    for (int cc = 0; cc < 2; cc++) {
        __syncthreads();
        // stage input: ci = cc*16 + 0..15, rows y0-1..y0+4, cols -1..32 (zero pad)
        for (int i = threadIdx.x; i < 16 * 6 * 34; i += 256) {
            int col = i % 34;
            int row = (i / 34) % 6;
            int cil = i / 204;
            int gy = y0 - 1 + row;
            int gx = col - 1;
            float vv = 0.f;
            if ((unsigned)gy < 32u && (unsigned)gx < 32u)
                vv = hin[(((size_t)(b * CH + cc * 16 + cil)) * HH + gy) * HH + gx];
            til[i] = vv;
        }
        __syncthreads();

        for (int cil = 0; cil < 16; cil++) {
            float in[6][3];
            const float* tp = &til[cil * 204];
#pragma unroll
            for (int rr2 = 0; rr2 < 6; rr2++)
#pragma unroll
                for (int dx = 0; dx < 3; dx++)
                    in[rr2][dx] = tp[rr2 * 34 + tx + dx];
            const float* wp = &wl[(ty * 32 + cc * 16 + cil) * 12];
            float4 wa = *(const float4*)wp;
            float4 wb = *(const float4*)(wp + 4);
            float  w8 = wp[8];
#pragma unroll
            for (int ry = 0; ry < 4; ry++) {
                float s = acc[ry];
                s = fmaf(in[ry + 0][0], wa.x, s);
                s = fmaf(in[ry + 0][1], wa.y, s);
                s = fmaf(in[ry + 0][2], wa.z, s);
                s = fmaf(in[ry + 1][0], wa.w, s);
                s = fmaf(in[ry + 1][1], wb.x, s);
                s = fmaf(in[ry + 1][2], wb.y, s);
                s = fmaf(in[ry + 2][0], wb.z, s);
                s = fmaf(in[ry + 2][1], wb.w, s);
                s = fmaf(in[ry + 2][2], w8,   s);
                acc[ry] = s;
            }
        }
    }

#pragma unroll
    for (int ry = 0; ry < 4; ry++) {
        size_t off = (((size_t)(b * CH + co)) * HH + (y0 + ry)) * HH + tx;
        float hc = hin[off];
        dst[off] = src[off] - (0.5f * hc + 0.5f * acc[ry]);
    }
}

// ---------------------------------------------------------------------------
// hits bincount over all scales' packed winners (multi-block, parallel)
__global__ __launch_bounds__(256) void bincount_kernel(const u64_t* __restrict__ pk,
                                                       float* __restrict__ hits, int n) {
    int i = blockIdx.x * 256 + threadIdx.x;
    if (i < n) {
        int idx = (int)(unsigned)(pk[i] & 0xFFFFFFFFull);
        atomicAdd(&hits[idx], 1.0f);
    }
}

// ---------------------------------------------------------------------------
// perplexity + loss finalize (single block; reads only the 4096-entry hist)
__global__ __launch_bounds__(256) void finalize_kernel(const float* __restrict__ hits,
                                                       const float* __restrict__ lacc,
                                                       float* __restrict__ outs) {
    __shared__ float sh[256];
    int t = threadIdx.x;
    // total = NROWS_TOTAL exactly (each row contributes one hit)
    const float tot = (float)NROWS_TOTAL;
    float ent = 0.f;
    for (int v = t; v < VV; v += 256) {
        float p = hits[v] / tot;
        ent += p * logf(p + 1e-10f);
    }
    sh[t] = ent;
    __syncthreads();
    for (int o = 128; o > 0; o >>= 1) {
        if (t < o) sh[t] += sh[t + o];
        __syncthreads();
    }
    if (t == 0) {
        // loss = SN*(1+BETA)*mean(f^2) = 7.5 * sumsq / 1048576  (f_hat stays 0)
        outs[0] = 7.5f * lacc[0] * (1.0f / (float)FELEMS);
        outs[1] = expf(-sh[0]);
    }
}

// ---------------------------------------------------------------------------
extern "C" void kernel_launch(void* const* d_in, const int* in_sizes, int n_in,
                              void* d_out, int out_size, void* d_ws, size_t ws_size,
                              hipStream_t stream) {
    const float* f   = (const float*)d_in[0];   // (32,32,32,32)
    const float* emb = (const float*)d_in[1];   // (4096,32)
    const float* phw = (const float*)d_in[2];   // (4,32,32,3,3)
    const float* phb = (const float*)d_in[3];   // (4,32)
    float* out = (float*)d_out;                 // f_hat (1048576) + loss + perplexity

    float* ws      = (float*)d_ws;
    float* hits    = ws;                              // [0, 4096)
    float* lacc    = ws + 8192;                       // [8192, 8448) padded
    u64_t* pkbase  = (u64_t*)(ws + 8448);             // 43680 u64 -> [8448, 95808)
    float* frest   = ws + 95808;                      // [95808, 1144384)
    half_t* zhi    = (half_t*)(ws + 1144384);         // 262144 halves = 131072 f
    half_t* zlo    = (half_t*)(ws + 1275456);         // ends 1406528
    float* nesqh   = ws + 1537600;                    // [1537600, 1541696)
    float* hup     = ws + 1541696;                    // [1541696, 2590272)
    half_t* ehi    = (half_t*)(ws + 2590272);         // 131072 halves = 65536 f
    half_t* elo    = (half_t*)(ws + 2655808);         // ends 2721344 (10.9 MB)

    // prep: emb split + nesqh + zero f_hat/hits/lacc + pk=+inf (no memset needed)
    prep_kernel<<<1024, 256, 0, stream>>>(emb, ehi, elo, nesqh, ws, pkbase, out);

    const int pns[6]   = {1, 2, 4, 8, 16, 32};
    const int sel[6]   = {0, 0, 1, 2, 3, 3};            // PHI_SEL
    const int pkoff[6] = {0, 32, 160, 672, 2720, 10912};

    for (int si = 0; si < 6; si++) {
        int pn = pns[si];
        int N = BS * pn * pn;
        u64_t* pk = pkbase + pkoff[si];
        const float* srcf = (si == 0) ? f : frest;      // frest not yet written at si=0

        if (si == 5) {
            argmin5_fused<<<dim3(512, 2), 256, 0, stream>>>(frest, ehi, elo, nesqh, pk);
        } else {
            if (si == 0)
                pool_big_kernel<true><<<N * CH, 256, 0, stream>>>(srcf, zhi, zlo, lacc, pn);
            else if (si == 1)
                pool_big_kernel<false><<<N * CH, 256, 0, stream>>>(srcf, zhi, zlo, lacc, pn);
            else if (si == 2)
                pool_wave_kernel<<<N * CH / 4, 256, 0, stream>>>(srcf, zhi, zlo);
            else
                pool_kernel<<<(N * CH) / 256, 256, 0, stream>>>(srcf, zhi, zlo, pn);

            if (si <= 2)        // N=32/128/512 -> grids 32/128/512 (r10 config)
                argmin_stage<1, 16><<<dim3(N / 16, 16), 256, 0, stream>>>(zhi, zlo, ehi, elo, nesqh, pk);
            else if (si == 3)   // N=2048 -> grid 1024 (r10 config)
                argmin_stage<1, 8><<<dim3(N / 16, 8), 256, 0, stream>>>(zhi, zlo, ehi, elo, nesqh, pk);
            else                // si=4, N=8192 -> grid 1024 (r10 config)
                argmin_stage<2, 4><<<dim3(N / 32, 4), 256, 0, stream>>>(zhi, zlo, ehi, elo, nesqh, pk);

            upsample_gather_kernel<<<FELEMS / 256, 256, 0, stream>>>(pk, emb, hup, pn);
            conv_phi_kernel<<<1024, 256, 0, stream>>>(
                hup, phw + (size_t)sel[si] * CH * CH * 9,
                phb + (size_t)sel[si] * CH, srcf, frest);
        }
    }

    bincount_kernel<<<(NROWS_TOTAL + 255) / 256, 256, 0, stream>>>(pkbase, hits, NROWS_TOTAL);
    finalize_kernel<<<1, 256, 0, stream>>>(hits, lacc, out + (out_size - 2));
}

// Round 16
// 423.433 us; speedup vs baseline: 1.0096x; 1.0096x over previous
//
#include <hip/hip_runtime.h>
#include <math.h>
#include <float.h>

// Problem constants (B=32, C=32, H=W=32, V=4096)
#define BS    32
#define CH    32
#define HH    32
#define VV    4096
#define FELEMS (BS*CH*HH*HH)   // 1048576
#define NROWS_TOTAL 43680      // sum over scales of B*pn*pn

typedef unsigned short ushort_t;
typedef unsigned long long u64_t;
typedef _Float16 half_t;
typedef __attribute__((ext_vector_type(8))) _Float16 half8;
typedef __attribute__((ext_vector_type(4))) float floatx4;

// 2-way fp16 split: x ~= h + l, residual <= 2^-22 |x|
__device__ inline void split2(float x, half_t* h, half_t* l) {
    half_t hh = (half_t)x;
    float r = x - (float)hh;
    *h = hh;
    *l = (half_t)r;
}

// fp32 -> sortable-descending key32 (bigger score => smaller key)
__device__ inline unsigned score_key32(float s) {
    unsigned u = __builtin_bit_cast(unsigned, s);
    unsigned m = (u & 0x80000000u) ? ~u : (u | 0x80000000u);  // monotone asc
    return ~m;                                                 // desc
}

// ---------------------------------------------------------------------------
// prep (grid 1024x256): emb fp16-split + nesqh, zero f_hat output, zero
// hits/lacc, init pk keys to +inf. Replaces the d_out memset.
__global__ __launch_bounds__(256) void prep_kernel(const float* __restrict__ emb,
                                                   half_t* __restrict__ ehi,
                                                   half_t* __restrict__ elo,
                                                   float* __restrict__ nesqh,
                                                   float* __restrict__ wszero,
                                                   u64_t* __restrict__ pk,
                                                   float* __restrict__ dout) {
    int gid = blockIdx.x * 256 + threadIdx.x;      // 262144 threads
    float4 z4 = {0.f, 0.f, 0.f, 0.f};
    *(float4*)(dout + (size_t)gid * 4) = z4;
    if (gid < 8448) wszero[gid] = 0.f;             // hits + pad + lacc
    if (gid < NROWS_TOTAL) pk[gid] = ~0ull;        // +inf keys
    if (gid < VV) {
        int v = gid;
        const float* ep = emb + (size_t)v * CH;
        float s = 0.f;
        half_t h[CH], l[CH];
#pragma unroll
        for (int i = 0; i < CH; i++) {
            float e = ep[i];
            s = fmaf(e, e, s);
            split2(e, &h[i], &l[i]);
        }
        nesqh[v] = -0.5f * s;
#pragma unroll
        for (int q = 0; q < 4; q++) {
            half8 H, L;
#pragma unroll
            for (int k = 0; k < 8; k++) {
                H[k] = h[q * 8 + k];
                L[k] = l[q * 8 + k];
            }
            *(half8*)(ehi + (size_t)v * CH + q * 8) = H;
            *(half8*)(elo + (size_t)v * CH + q * 8) = L;
        }
    }
}

// ---------------------------------------------------------------------------
// mean-pool, pn = 8/16/32: thread per (n,c); n=(b*pn+i)*pn+j.
// pn=32 (ps=1) is the identity split used for si=5.
__global__ __launch_bounds__(256) void pool_kernel(const float* __restrict__ f,
                                                   half_t* __restrict__ zhi,
                                                   half_t* __restrict__ zlo, int pn) {
    int tid = blockIdx.x * 256 + threadIdx.x;
    int c = tid % CH;
    int n = tid / CH;
    if (n >= BS * pn * pn) return;
    int j = n % pn, i = (n / pn) % pn, b = n / (pn * pn);
    int ps = HH / pn;
    const float* base = f + (((size_t)(b * CH + c) * HH) + i * ps) * HH + j * ps;
    float s = 0.f;
    for (int dy = 0; dy < ps; dy++)
        for (int dx = 0; dx < ps; dx++)
            s += base[dy * HH + dx];
    s *= (1.0f / (ps * ps));
    split2(s, &zhi[tid], &zlo[tid]);
}

// mean-pool, pn = 1/2: block per (n,c) pair; SQ also accumulates sumsq (si=0).
template <bool SQ>
__global__ __launch_bounds__(256) void pool_big_kernel(const float* __restrict__ f,
                                                       half_t* __restrict__ zhi,
                                                       half_t* __restrict__ zlo,
                                                       float* __restrict__ lacc, int pn) {
    int pair = blockIdx.x;            // pair = n*CH + c
    int c = pair & 31;
    int n = pair >> 5;
    int j = n % pn, i = (n / pn) % pn, b = n / (pn * pn);
    int ps = HH / pn;                 // 32 or 16
    int npx = ps * ps;
    const float* base = f + (((size_t)(b * CH + c) * HH) + i * ps) * HH + j * ps;
    float s = 0.f, s2 = 0.f;
    for (int p = threadIdx.x; p < npx; p += 256) {
        float v = base[(p / ps) * HH + (p % ps)];
        s += v;
        if (SQ) s2 = fmaf(v, v, s2);
    }
    __shared__ float sh[256];
    sh[threadIdx.x] = s;
    __syncthreads();
    for (int o = 128; o > 0; o >>= 1) {
        if (threadIdx.x < o) sh[threadIdx.x] += sh[threadIdx.x + o];
        __syncthreads();
    }
    if (threadIdx.x == 0) {
        float t = sh[0] * (1.0f / npx);
        int o = n * CH + c;
        split2(t, &zhi[o], &zlo[o]);
    }
    if (SQ) {
        __syncthreads();
        sh[threadIdx.x] = s2;
        __syncthreads();
        for (int o = 128; o > 0; o >>= 1) {
            if (threadIdx.x < o) sh[threadIdx.x] += sh[threadIdx.x + o];
            __syncthreads();
        }
        if (threadIdx.x == 0) atomicAdd(lacc, sh[0]);
    }
}

// mean-pool, pn = 4 (ps=8, 64 px): wave per (n,c) pair, shuffle reduce
__global__ __launch_bounds__(256) void pool_wave_kernel(const float* __restrict__ f,
                                                        half_t* __restrict__ zhi,
                                                        half_t* __restrict__ zlo) {
    const int pn = 4, ps = 8;
    int lane = threadIdx.x & 63;
    int pair = blockIdx.x * 4 + (threadIdx.x >> 6);
    int c = pair & 31;
    int n = pair >> 5;
    int j = n % pn, i = (n / pn) % pn, b = n / (pn * pn);
    const float* base = f + (((size_t)(b * CH + c) * HH) + i * ps) * HH + j * ps;
    float s = base[(lane >> 3) * HH + (lane & 7)];
#pragma unroll
    for (int m = 1; m < 64; m <<= 1) s += __shfl_xor(s, m, 64);
    if (lane == 0) {
        float t = s * (1.0f / 64.0f);
        int o = n * CH + c;
        split2(t, &zhi[o], &zlo[o]);
    }
}

// ---------------------------------------------------------------------------
// 3-MFMA fp16 score chain for one 16-row group vs one 16-code tile
// score = z.e - 0.5|e|^2 = ah.bh + ah.bl + al.bh  (al.bl <= 2^-22 dropped)
__device__ inline floatx4 score_chain(half8 ah, half8 al,
                                      half8 bh, half8 bl, floatx4 ehv) {
    floatx4 acc;
    acc = __builtin_amdgcn_mfma_f32_16x16x32_f16(ah, bh, ehv, 0, 0, 0);
    acc = __builtin_amdgcn_mfma_f32_16x16x32_f16(ah, bl, acc, 0, 0, 0);
    acc = __builtin_amdgcn_mfma_f32_16x16x32_f16(al, bh, acc, 0, 0, 0);
    return acc;
}

__device__ inline void sel4(const floatx4& acc, int v, float* best, int* bidx) {
#pragma unroll
    for (int r = 0; r < 4; r++) {
        // strict >: lane-local scan is increasing v -> keeps lowest v on tie
        if (acc[r] > best[r]) { best[r] = acc[r]; bidx[r] = v; }
    }
}

// argmin core (r10/r14-proven 1-deep prefetch; 2-deep variant regressed).
// Wave wv scans TPW v-tiles from t0+wv*TPW over RT 16-row tiles.
// Deferred-select interleave (RT>=2). Winner per row merged cross-block via
// packed-key atomicMin (max score, lowest idx on tie == jnp.argmin).
template <int RT, int TPW>
__device__ inline void argmin_body(const half8* a1, const half8* a2,
                                   const half_t* __restrict__ ehi,
                                   const half_t* __restrict__ elo,
                                   const float* __restrict__ nesqh,
                                   u64_t* __restrict__ pk, int row0, int t0) {
    const int tid  = threadIdx.x;
    const int wv   = tid >> 6;
    const int lane = tid & 63;
    const int col  = lane & 15;
    const int quad = lane >> 4;

    float best[RT][4];
    int   bidx[RT][4];
#pragma unroll
    for (int rt = 0; rt < RT; rt++)
#pragma unroll
        for (int r = 0; r < 4; r++) { best[rt][r] = -FLT_MAX; bidx[rt][r] = 0; }

    int t = t0 + wv * TPW;
    const int tend = t + TPW;

    // prefetch tile t
    size_t eoff = ((size_t)((t << 4) + col) << 5) + (quad << 3);
    half8 nb1 = *(const half8*)(ehi + eoff);
    half8 nb2 = *(const half8*)(elo + eoff);
    float neh = nesqh[(t << 4) + col];

    floatx4 acc[RT];
    int vprev = 0;
    if (RT > 1) acc[RT - 1] = floatx4{-FLT_MAX, -FLT_MAX, -FLT_MAX, -FLT_MAX};

    for (; t < tend; t++) {
        const half8 b1 = nb1, b2 = nb2;
        const floatx4 ehv = {neh, neh, neh, neh};
        const int vcur = (t << 4) + col;
        // prefetch t+1 (clamped) before consuming current
        const int tn = (t + 1 < tend) ? (t + 1) : t;
        const size_t eoff2 = ((size_t)((tn << 4) + col) << 5) + (quad << 3);
        nb1 = *(const half8*)(ehi + eoff2);
        nb2 = *(const half8*)(elo + eoff2);
        neh = nesqh[(tn << 4) + col];

        if (RT == 1) {
            acc[0] = score_chain(a1[0], a2[0], b1, b2, ehv);
            sel4(acc[0], vcur, best[0], bidx[0]);
        } else {
            acc[0] = score_chain(a1[0], a2[0], b1, b2, ehv);
            sel4(acc[RT - 1], vprev, best[RT - 1], bidx[RT - 1]);  // deferred
#pragma unroll
            for (int rt = 1; rt < RT; rt++) {
                acc[rt] = score_chain(a1[rt], a2[rt], b1, b2, ehv);
                sel4(acc[rt - 1], vcur, best[rt - 1], bidx[rt - 1]);
            }
            vprev = vcur;
        }
    }
    if (RT > 1) sel4(acc[RT - 1], vprev, best[RT - 1], bidx[RT - 1]);

    // reduce across the 16 cols (v within tile) of each quad group
#pragma unroll
    for (int m = 1; m < 16; m <<= 1) {
#pragma unroll
        for (int rt = 0; rt < RT; rt++)
#pragma unroll
            for (int r = 0; r < 4; r++) {
                float s2 = __shfl_xor(best[rt][r], m, 64);
                int   v2 = __shfl_xor(bidx[rt][r], m, 64);
                if (s2 > best[rt][r] ||
                    (s2 == best[rt][r] && v2 < bidx[rt][r])) {
                    best[rt][r] = s2; bidx[rt][r] = v2;
                }
            }
    }

    __shared__ float sbs[4 * RT * 16];
    __shared__ int   sbi[4 * RT * 16];
    if (col == 0) {
#pragma unroll
        for (int rt = 0; rt < RT; rt++)
#pragma unroll
            for (int r = 0; r < 4; r++) {
                int row = rt * 16 + (quad << 2) + r;
                sbs[wv * RT * 16 + row] = best[rt][r];
                sbi[wv * RT * 16 + row] = bidx[rt][r];
            }
    }
    __syncthreads();
    if (tid < RT * 16) {
        float s = sbs[tid];
        int   v = sbi[tid];
        for (int w = 1; w < 4; w++) {
            float s2 = sbs[w * RT * 16 + tid];
            int   v2 = sbi[w * RT * 16 + tid];
            if (s2 > s || (s2 == s && v2 < v)) { s = s2; v = v2; }
        }
        u64_t key = ((u64_t)score_key32(s) << 32) | (unsigned)v;
        atomicMin(pk + row0 + tid, key);
    }
}

// generic stage: z-splits from memory (cheap 8-load prologue -> VS is nearly
// free). grid = (nRowBlocks, VS)
template <int RT, int VS>
__global__ __launch_bounds__(256) void argmin_stage(const half_t* __restrict__ zhi,
                                                    const half_t* __restrict__ zlo,
                                                    const half_t* __restrict__ ehi,
                                                    const half_t* __restrict__ elo,
                                                    const float* __restrict__ nesqh,
                                                    u64_t* __restrict__ pk) {
    const int lane = threadIdx.x & 63;
    const int col  = lane & 15;
    const int quad = lane >> 4;
    const int row0 = blockIdx.x * (16 * RT);

    half8 a1[RT], a2[RT];
#pragma unroll
    for (int rt = 0; rt < RT; rt++) {
        size_t off = ((size_t)(row0 + rt * 16 + col) << 5) + (quad << 3);
        a1[rt] = *(const half8*)(zhi + off);
        a2[rt] = *(const half8*)(zlo + off);
    }
    argmin_body<RT, 64 / VS>(a1, a2, ehi, elo, nesqh, pk,
                             row0, (int)blockIdx.y * (256 / VS));
}

// ---------------------------------------------------------------------------
// bicubic weights, a=-0.75, half-pixel, edge clamp (matches ref _bicubic_mat)
__device__ inline void cubic_w(float xs, int pn, int* ix, float* w) {
    const float a = -0.75f;
    float xf = floorf(xs);
    int x0 = (int)xf;
    float t = xs - xf;
#pragma unroll
    for (int j = -1; j <= 2; j++) {
        float d = fabsf(t - (float)j);
        float ww;
        if (d < 1.0f)      ww = ((a + 2.0f) * d - (a + 3.0f)) * d * d + 1.0f;
        else if (d < 2.0f) ww = ((a * d - 5.0f * a) * d + 8.0f * a) * d - 4.0f * a;
        else               ww = 0.0f;
        int xi = x0 + j;
        xi = xi < 0 ? 0 : (xi > pn - 1 ? pn - 1 : xi);
        ix[j + 1] = xi;
        w[j + 1]  = ww;
    }
}

// Fused gather + bicubic upsample from packed keys (idx = low 32 bits).
// Thread mapping [b][c][Y][X], X minor -> coalesced hup writes; scattered
// emb gathers absorbed by L1/L2 (emb = 512 KB). (r5-verified layout.)
__global__ __launch_bounds__(256) void upsample_gather_kernel(const u64_t* __restrict__ pk,
                                                              const float* __restrict__ emb,
                                                              float* __restrict__ hu, int pn) {
    int tid = blockIdx.x * 256 + threadIdx.x;   // [b][c][Y][X]
    int X = tid & 31;
    int Y = (tid >> 5) & 31;
    int c = (tid >> 10) & 31;
    int b = tid >> 15;
    float scale = (float)pn / (float)HH;
    int iy[4], ix[4];
    float wy[4], wx[4];
    cubic_w(((float)Y + 0.5f) * scale - 0.5f, pn, iy, wy);
    cubic_w(((float)X + 0.5f) * scale - 0.5f, pn, ix, wx);
    const u64_t* ib = pk + b * pn * pn;
    float s = 0.f;
#pragma unroll
    for (int a = 0; a < 4; a++) {
        float rsum = 0.f;
#pragma unroll
        for (int b2 = 0; b2 < 4; b2++) {
            int idx = (int)(unsigned)(ib[iy[a] * pn + ix[b2]] & 0xFFFFFFFFull);
            rsum = fmaf(emb[(size_t)idx * CH + c], wx[b2], rsum);
        }
        s = fmaf(rsum, wy[a], s);
    }
    hu[tid] = s;
}

// ---------------------------------------------------------------------------
// Phi + residual: dst = src - (0.5*h + 0.5*(conv3x3(h)+bias))
// grid: b(32) x yt(8) x co-quarter(4) = 1024 blocks (4 blocks/CU);
// block 256 = tx(32) x ty(8); thread: 4 rows x col tx x 1 co (co = coq*8+ty).
// (r9/r10-proven shape. r11's 2-row variant blew VGPR to 180 — keep as-is.)
__global__ __launch_bounds__(256) void conv_phi_kernel(const float* __restrict__ hin,
                                                       const float* __restrict__ w,
                                                       const float* __restrict__ bias,
                                                       const float* __restrict__ src,
                                                       float* __restrict__ dst) {
    const int coq = blockIdx.x & 3;
    const int yt  = (blockIdx.x >> 2) & 7;
    const int b   = blockIdx.x >> 5;
    const int tx  = threadIdx.x & 31;
    const int ty  = threadIdx.x >> 5;     // 0..7
    const int y0  = yt * 4;

    __shared__ float wl[8 * 32 * 12];     // 12 KB
    __shared__ float til[16 * 6 * 34];    // 13.1 KB

    {
        const float* wsrc = w + (size_t)coq * 8 * CH * 9;
        for (int i = threadIdx.x; i < 8 * 32 * 12; i += 256) {
            int k = i % 12;
            wl[i] = (k < 9) ? wsrc[(i / 12) * 9 + k] : 0.f;
        }
    }

    const int co = coq * 8 + ty;
    float acc[4];
#pragma unroll
    for (int ry = 0; ry < 4; ry++) acc[ry] = bias[co];

    for (int cc = 0; cc < 2; cc++) {
        __syncthreads();
        // stage input: ci = cc*16 + 0..15, rows y0-1..y0+4, cols -1..32 (zero pad)
        for (int i = threadIdx.x; i < 16 * 6 * 34; i += 256) {
            int col = i % 34;
            int row = (i / 34) % 6;
            int cil = i / 204;
            int gy = y0 - 1 + row;
            int gx = col - 1;
            float vv = 0.f;
            if ((unsigned)gy < 32u && (unsigned)gx < 32u)
                vv = hin[(((size_t)(b * CH + cc * 16 + cil)) * HH + gy) * HH + gx];
            til[i] = vv;
        }
        __syncthreads();

        for (int cil = 0; cil < 16; cil++) {
            float in[6][3];
            const float* tp = &til[cil * 204];
#pragma unroll
            for (int rr2 = 0; rr2 < 6; rr2++)
#pragma unroll
                for (int dx = 0; dx < 3; dx++)
                    in[rr2][dx] = tp[rr2 * 34 + tx + dx];
            const float* wp = &wl[(ty * 32 + cc * 16 + cil) * 12];
            float4 wa = *(const float4*)wp;
            float4 wb = *(const float4*)(wp + 4);
            float  w8 = wp[8];
#pragma unroll
            for (int ry = 0; ry < 4; ry++) {
                float s = acc[ry];
                s = fmaf(in[ry + 0][0], wa.x, s);
                s = fmaf(in[ry + 0][1], wa.y, s);
                s = fmaf(in[ry + 0][2], wa.z, s);
                s = fmaf(in[ry + 1][0], wa.w, s);
                s = fmaf(in[ry + 1][1], wb.x, s);
                s = fmaf(in[ry + 1][2], wb.y, s);
                s = fmaf(in[ry + 2][0], wb.z, s);
                s = fmaf(in[ry + 2][1], wb.w, s);
                s = fmaf(in[ry + 2][2], w8,   s);
                acc[ry] = s;
            }
        }
    }

#pragma unroll
    for (int ry = 0; ry < 4; ry++) {
        size_t off = (((size_t)(b * CH + co)) * HH + (y0 + ry)) * HH + tx;
        float hc = hin[off];
        dst[off] = src[off] - (0.5f * hc + 0.5f * acc[ry]);
    }
}

// ---------------------------------------------------------------------------
// hits bincount over all scales' packed winners (multi-block, parallel)
__global__ __launch_bounds__(256) void bincount_kernel(const u64_t* __restrict__ pk,
                                                       float* __restrict__ hits, int n) {
    int i = blockIdx.x * 256 + threadIdx.x;
    if (i < n) {
        int idx = (int)(unsigned)(pk[i] & 0xFFFFFFFFull);
        atomicAdd(&hits[idx], 1.0f);
    }
}

// ---------------------------------------------------------------------------
// perplexity + loss finalize (single block; reads only the 4096-entry hist)
__global__ __launch_bounds__(256) void finalize_kernel(const float* __restrict__ hits,
                                                       const float* __restrict__ lacc,
                                                       float* __restrict__ outs) {
    __shared__ float sh[256];
    int t = threadIdx.x;
    // total = NROWS_TOTAL exactly (each row contributes one hit)
    const float tot = (float)NROWS_TOTAL;
    float ent = 0.f;
    for (int v = t; v < VV; v += 256) {
        float p = hits[v] / tot;
        ent += p * logf(p + 1e-10f);
    }
    sh[t] = ent;
    __syncthreads();
    for (int o = 128; o > 0; o >>= 1) {
        if (t < o) sh[t] += sh[t + o];
        __syncthreads();
    }
    if (t == 0) {
        // loss = SN*(1+BETA)*mean(f^2) = 7.5 * sumsq / 1048576  (f_hat stays 0)
        outs[0] = 7.5f * lacc[0] * (1.0f / (float)FELEMS);
        outs[1] = expf(-sh[0]);
    }
}

// ---------------------------------------------------------------------------
extern "C" void kernel_launch(void* const* d_in, const int* in_sizes, int n_in,
                              void* d_out, int out_size, void* d_ws, size_t ws_size,
                              hipStream_t stream) {
    const float* f   = (const float*)d_in[0];   // (32,32,32,32)
    const float* emb = (const float*)d_in[1];   // (4096,32)
    const float* phw = (const float*)d_in[2];   // (4,32,32,3,3)
    const float* phb = (const float*)d_in[3];   // (4,32)
    float* out = (float*)d_out;                 // f_hat (1048576) + loss + perplexity

    float* ws      = (float*)d_ws;
    float* hits    = ws;                              // [0, 4096)
    float* lacc    = ws + 8192;                       // [8192, 8448) padded
    u64_t* pkbase  = (u64_t*)(ws + 8448);             // 43680 u64 -> [8448, 95808)
    float* frest   = ws + 95808;                      // [95808, 1144384)
    half_t* zhi    = (half_t*)(ws + 1144384);         // 262144 halves (si<=4)
    half_t* zlo    = (half_t*)(ws + 1275456);         // ends 1406528
    float* nesqh   = ws + 1537600;                    // [1537600, 1541696)
    float* hup     = ws + 1541696;                    // [1541696, 2590272) 4MB
    half_t* ehi    = (half_t*)(ws + 2590272);         // 131072 halves = 65536 f
    half_t* elo    = (half_t*)(ws + 2655808);         // ends 2721344 (10.9 MB)

    // si=5 z-splits overlay the hup region (hup is dead after the si=4 conv):
    // 2 x 1048576 halves = 4 MB exactly.
    half_t* zhi5 = (half_t*)hup;
    half_t* zlo5 = (half_t*)(hup + 524288);

    // prep: emb split + nesqh + zero f_hat/hits/lacc + pk=+inf (no memset needed)
    prep_kernel<<<1024, 256, 0, stream>>>(emb, ehi, elo, nesqh, ws, pkbase, out);

    const int pns[6]   = {1, 2, 4, 8, 16, 32};
    const int sel[6]   = {0, 0, 1, 2, 3, 3};            // PHI_SEL
    const int pkoff[6] = {0, 32, 160, 672, 2720, 10912};

    for (int si = 0; si < 6; si++) {
        int pn = pns[si];
        int N = BS * pn * pn;
        u64_t* pk = pkbase + pkoff[si];
        const float* srcf = (si == 0) ? f : frest;      // frest not yet written at si=0

        if (si == 5) {
            // identity pool (ps=1) -> z-splits in hup region; then the generic
            // stage whose prologue is 8 vector loads -> VS=4 is nearly free.
            pool_kernel<<<(N * CH) / 256, 256, 0, stream>>>(frest, zhi5, zlo5, 32);
            argmin_stage<4, 4><<<dim3(N / 64, 4), 256, 0, stream>>>(zhi5, zlo5, ehi, elo, nesqh, pk);
        } else {
            if (si == 0)
                pool_big_kernel<true><<<N * CH, 256, 0, stream>>>(srcf, zhi, zlo, lacc, pn);
            else if (si == 1)
                pool_big_kernel<false><<<N * CH, 256, 0, stream>>>(srcf, zhi, zlo, lacc, pn);
            else if (si == 2)
                pool_wave_kernel<<<N * CH / 4, 256, 0, stream>>>(srcf, zhi, zlo);
            else
                pool_kernel<<<(N * CH) / 256, 256, 0, stream>>>(srcf, zhi, zlo, pn);

            if (si <= 2)        // N=32/128/512 -> grids 32/128/512 (r10 config)
                argmin_stage<1, 16><<<dim3(N / 16, 16), 256, 0, stream>>>(zhi, zlo, ehi, elo, nesqh, pk);
            else if (si == 3)   // N=2048 -> grid 1024 (r10 config)
                argmin_stage<1, 8><<<dim3(N / 16, 8), 256, 0, stream>>>(zhi, zlo, ehi, elo, nesqh, pk);
            else                // si=4, N=8192 -> grid 1024 (r10 config)
                argmin_stage<2, 4><<<dim3(N / 32, 4), 256, 0, stream>>>(zhi, zlo, ehi, elo, nesqh, pk);

            upsample_gather_kernel<<<FELEMS / 256, 256, 0, stream>>>(pk, emb, hup, pn);
            conv_phi_kernel<<<1024, 256, 0, stream>>>(
                hup, phw + (size_t)sel[si] * CH * CH * 9,
                phb + (size_t)sel[si] * CH, srcf, frest);
        }
    }

    bincount_kernel<<<(NROWS_TOTAL + 255) / 256, 256, 0, stream>>>(pkbase, hits, NROWS_TOTAL);
    finalize_kernel<<<1, 256, 0, stream>>>(hits, lacc, out + (out_size - 2));
}

// Round 17
// 411.842 us; speedup vs baseline: 1.0380x; 1.0281x over previous
//
#include <hip/hip_runtime.h>
#include <math.h>
#include <float.h>

// Problem constants (B=32, C=32, H=W=32, V=4096)
#define BS    32
#define CH    32
#define HH    32
#define VV    4096
#define FELEMS (BS*CH*HH*HH)   // 1048576
#define NROWS_TOTAL 43680      // sum over scales of B*pn*pn

typedef unsigned short ushort_t;
typedef unsigned long long u64_t;
typedef _Float16 half_t;
typedef __attribute__((ext_vector_type(8))) _Float16 half8;
typedef __attribute__((ext_vector_type(4))) float floatx4;

// 2-way fp16 split: x ~= h + l, residual <= 2^-22 |x|
__device__ inline void split2(float x, half_t* h, half_t* l) {
    half_t hh = (half_t)x;
    float r = x - (float)hh;
    *h = hh;
    *l = (half_t)r;
}

// fp32 -> sortable-descending key32 (bigger score => smaller key)
__device__ inline unsigned score_key32(float s) {
    unsigned u = __builtin_bit_cast(unsigned, s);
    unsigned m = (u & 0x80000000u) ? ~u : (u | 0x80000000u);  // monotone asc
    return ~m;                                                 // desc
}

// ---------------------------------------------------------------------------
// prep (grid 1024x256): emb fp16-split + nesqh, zero f_hat output, zero
// hits/lacc, init pk keys to +inf. Replaces the d_out memset.
__global__ __launch_bounds__(256) void prep_kernel(const float* __restrict__ emb,
                                                   half_t* __restrict__ ehi,
                                                   half_t* __restrict__ elo,
                                                   float* __restrict__ nesqh,
                                                   float* __restrict__ wszero,
                                                   u64_t* __restrict__ pk,
                                                   float* __restrict__ dout) {
    int gid = blockIdx.x * 256 + threadIdx.x;      // 262144 threads
    float4 z4 = {0.f, 0.f, 0.f, 0.f};
    *(float4*)(dout + (size_t)gid * 4) = z4;
    if (gid < 8448) wszero[gid] = 0.f;             // hits + pad + lacc
    if (gid < NROWS_TOTAL) pk[gid] = ~0ull;        // +inf keys
    if (gid < VV) {
        int v = gid;
        const float* ep = emb + (size_t)v * CH;
        float s = 0.f;
        half_t h[CH], l[CH];
#pragma unroll
        for (int i = 0; i < CH; i++) {
            float e = ep[i];
            s = fmaf(e, e, s);
            split2(e, &h[i], &l[i]);
        }
        nesqh[v] = -0.5f * s;
#pragma unroll
        for (int q = 0; q < 4; q++) {
            half8 H, L;
#pragma unroll
            for (int k = 0; k < 8; k++) {
                H[k] = h[q * 8 + k];
                L[k] = l[q * 8 + k];
            }
            *(half8*)(ehi + (size_t)v * CH + q * 8) = H;
            *(half8*)(elo + (size_t)v * CH + q * 8) = L;
        }
    }
}

// ---------------------------------------------------------------------------
// mean-pool, pn = 8/16: thread per (n,c); n=(b*pn+i)*pn+j
__global__ __launch_bounds__(256) void pool_kernel(const float* __restrict__ f,
                                                   half_t* __restrict__ zhi,
                                                   half_t* __restrict__ zlo, int pn) {
    int tid = blockIdx.x * 256 + threadIdx.x;
    int c = tid % CH;
    int n = tid / CH;
    if (n >= BS * pn * pn) return;
    int j = n % pn, i = (n / pn) % pn, b = n / (pn * pn);
    int ps = HH / pn;
    const float* base = f + (((size_t)(b * CH + c) * HH) + i * ps) * HH + j * ps;
    float s = 0.f;
    for (int dy = 0; dy < ps; dy++)
        for (int dx = 0; dx < ps; dx++)
            s += base[dy * HH + dx];
    s *= (1.0f / (ps * ps));
    split2(s, &zhi[tid], &zlo[tid]);
}

// mean-pool, pn = 1/2: block per (n,c) pair; SQ also accumulates sumsq (si=0).
template <bool SQ>
__global__ __launch_bounds__(256) void pool_big_kernel(const float* __restrict__ f,
                                                       half_t* __restrict__ zhi,
                                                       half_t* __restrict__ zlo,
                                                       float* __restrict__ lacc, int pn) {
    int pair = blockIdx.x;            // pair = n*CH + c
    int c = pair & 31;
    int n = pair >> 5;
    int j = n % pn, i = (n / pn) % pn, b = n / (pn * pn);
    int ps = HH / pn;                 // 32 or 16
    int npx = ps * ps;
    const float* base = f + (((size_t)(b * CH + c) * HH) + i * ps) * HH + j * ps;
    float s = 0.f, s2 = 0.f;
    for (int p = threadIdx.x; p < npx; p += 256) {
        float v = base[(p / ps) * HH + (p % ps)];
        s += v;
        if (SQ) s2 = fmaf(v, v, s2);
    }
    __shared__ float sh[256];
    sh[threadIdx.x] = s;
    __syncthreads();
    for (int o = 128; o > 0; o >>= 1) {
        if (threadIdx.x < o) sh[threadIdx.x] += sh[threadIdx.x + o];
        __syncthreads();
    }
    if (threadIdx.x == 0) {
        float t = sh[0] * (1.0f / npx);
        int o = n * CH + c;
        split2(t, &zhi[o], &zlo[o]);
    }
    if (SQ) {
        __syncthreads();
        sh[threadIdx.x] = s2;
        __syncthreads();
        for (int o = 128; o > 0; o >>= 1) {
            if (threadIdx.x < o) sh[threadIdx.x] += sh[threadIdx.x + o];
            __syncthreads();
        }
        if (threadIdx.x == 0) atomicAdd(lacc, sh[0]);
    }
}

// mean-pool, pn = 4 (ps=8, 64 px): wave per (n,c) pair, shuffle reduce
__global__ __launch_bounds__(256) void pool_wave_kernel(const float* __restrict__ f,
                                                        half_t* __restrict__ zhi,
                                                        half_t* __restrict__ zlo) {
    const int pn = 4, ps = 8;
    int lane = threadIdx.x & 63;
    int pair = blockIdx.x * 4 + (threadIdx.x >> 6);
    int c = pair & 31;
    int n = pair >> 5;
    int j = n % pn, i = (n / pn) % pn, b = n / (pn * pn);
    const float* base = f + (((size_t)(b * CH + c) * HH) + i * ps) * HH + j * ps;
    float s = base[(lane >> 3) * HH + (lane & 7)];
#pragma unroll
    for (int m = 1; m < 64; m <<= 1) s += __shfl_xor(s, m, 64);
    if (lane == 0) {
        float t = s * (1.0f / 64.0f);
        int o = n * CH + c;
        split2(t, &zhi[o], &zlo[o]);
    }
}

// ---------------------------------------------------------------------------
// 3-MFMA fp16 score chain for one 16-row group vs one 16-code tile
// score = z.e - 0.5|e|^2 = ah.bh + ah.bl + al.bh  (al.bl <= 2^-22 dropped)
__device__ inline floatx4 score_chain(half8 ah, half8 al,
                                      half8 bh, half8 bl, floatx4 ehv) {
    floatx4 acc;
    acc = __builtin_amdgcn_mfma_f32_16x16x32_f16(ah, bh, ehv, 0, 0, 0);
    acc = __builtin_amdgcn_mfma_f32_16x16x32_f16(ah, bl, acc, 0, 0, 0);
    acc = __builtin_amdgcn_mfma_f32_16x16x32_f16(al, bh, acc, 0, 0, 0);
    return acc;
}

__device__ inline void sel4(const floatx4& acc, int v, float* best, int* bidx) {
#pragma unroll
    for (int r = 0; r < 4; r++) {
        // strict >: lane-local scan is increasing v -> keeps lowest v on tie
        if (acc[r] > best[r]) { best[r] = acc[r]; bidx[r] = v; }
    }
}

// argmin core (1-deep prefetch — the proven fastest of four structural
// variants: 2-deep pipe, VS ladders, pooled-stage all regressed or tied).
// Wave wv scans TPW v-tiles from t0+wv*TPW over RT 16-row tiles.
// Deferred-select interleave (RT>=2). Winner per row merged cross-block via
// packed-key atomicMin (max score, lowest idx on tie == jnp.argmin).
template <int RT, int TPW>
__device__ inline void argmin_body(const half8* a1, const half8* a2,
                                   const half_t* __restrict__ ehi,
                                   const half_t* __restrict__ elo,
                                   const float* __restrict__ nesqh,
                                   u64_t* __restrict__ pk, int row0, int t0) {
    const int tid  = threadIdx.x;
    const int wv   = tid >> 6;
    const int lane = tid & 63;
    const int col  = lane & 15;
    const int quad = lane >> 4;

    float best[RT][4];
    int   bidx[RT][4];
#pragma unroll
    for (int rt = 0; rt < RT; rt++)
#pragma unroll
        for (int r = 0; r < 4; r++) { best[rt][r] = -FLT_MAX; bidx[rt][r] = 0; }

    int t = t0 + wv * TPW;
    const int tend = t + TPW;

    // prefetch tile t
    size_t eoff = ((size_t)((t << 4) + col) << 5) + (quad << 3);
    half8 nb1 = *(const half8*)(ehi + eoff);
    half8 nb2 = *(const half8*)(elo + eoff);
    float neh = nesqh[(t << 4) + col];

    floatx4 acc[RT];
    int vprev = 0;
    if (RT > 1) acc[RT - 1] = floatx4{-FLT_MAX, -FLT_MAX, -FLT_MAX, -FLT_MAX};

    for (; t < tend; t++) {
        const half8 b1 = nb1, b2 = nb2;
        const floatx4 ehv = {neh, neh, neh, neh};
        const int vcur = (t << 4) + col;
        // prefetch t+1 (clamped) before consuming current
        const int tn = (t + 1 < tend) ? (t + 1) : t;
        const size_t eoff2 = ((size_t)((tn << 4) + col) << 5) + (quad << 3);
        nb1 = *(const half8*)(ehi + eoff2);
        nb2 = *(const half8*)(elo + eoff2);
        neh = nesqh[(tn << 4) + col];

        if (RT == 1) {
            acc[0] = score_chain(a1[0], a2[0], b1, b2, ehv);
            sel4(acc[0], vcur, best[0], bidx[0]);
        } else {
            acc[0] = score_chain(a1[0], a2[0], b1, b2, ehv);
            sel4(acc[RT - 1], vprev, best[RT - 1], bidx[RT - 1]);  // deferred
#pragma unroll
            for (int rt = 1; rt < RT; rt++) {
                acc[rt] = score_chain(a1[rt], a2[rt], b1, b2, ehv);
                sel4(acc[rt - 1], vcur, best[rt - 1], bidx[rt - 1]);
            }
            vprev = vcur;
        }
    }
    if (RT > 1) sel4(acc[RT - 1], vprev, best[RT - 1], bidx[RT - 1]);

    // reduce across the 16 cols (v within tile) of each quad group
#pragma unroll
    for (int m = 1; m < 16; m <<= 1) {
#pragma unroll
        for (int rt = 0; rt < RT; rt++)
#pragma unroll
            for (int r = 0; r < 4; r++) {
                float s2 = __shfl_xor(best[rt][r], m, 64);
                int   v2 = __shfl_xor(bidx[rt][r], m, 64);
                if (s2 > best[rt][r] ||
                    (s2 == best[rt][r] && v2 < bidx[rt][r])) {
                    best[rt][r] = s2; bidx[rt][r] = v2;
                }
            }
    }

    __shared__ float sbs[4 * RT * 16];
    __shared__ int   sbi[4 * RT * 16];
    if (col == 0) {
#pragma unroll
        for (int rt = 0; rt < RT; rt++)
#pragma unroll
            for (int r = 0; r < 4; r++) {
                int row = rt * 16 + (quad << 2) + r;
                sbs[wv * RT * 16 + row] = best[rt][r];
                sbi[wv * RT * 16 + row] = bidx[rt][r];
            }
    }
    __syncthreads();
    if (tid < RT * 16) {
        float s = sbs[tid];
        int   v = sbi[tid];
        for (int w = 1; w < 4; w++) {
            float s2 = sbs[w * RT * 16 + tid];
            int   v2 = sbi[w * RT * 16 + tid];
            if (s2 > s || (s2 == s && v2 < v)) { s = s2; v = v2; }
        }
        u64_t key = ((u64_t)score_key32(s) << 32) | (unsigned)v;
        atomicMin(pk + row0 + tid, key);
    }
}

// generic stage: z-splits from memory. grid = (nRowBlocks, VS)
template <int RT, int VS>
__global__ __launch_bounds__(256) void argmin_stage(const half_t* __restrict__ zhi,
                                                    const half_t* __restrict__ zlo,
                                                    const half_t* __restrict__ ehi,
                                                    const half_t* __restrict__ elo,
                                                    const float* __restrict__ nesqh,
                                                    u64_t* __restrict__ pk) {
    const int lane = threadIdx.x & 63;
    const int col  = lane & 15;
    const int quad = lane >> 4;
    const int row0 = blockIdx.x * (16 * RT);

    half8 a1[RT], a2[RT];
#pragma unroll
    for (int rt = 0; rt < RT; rt++) {
        size_t off = ((size_t)(row0 + rt * 16 + col) << 5) + (quad << 3);
        a1[rt] = *(const half8*)(zhi + off);
        a2[rt] = *(const half8*)(zlo + off);
    }
    argmin_body<RT, 64 / VS>(a1, a2, ehi, elo, nesqh, pk,
                             row0, (int)blockIdx.y * (256 / VS));
}

// si=5 fused: pool is identity (pn=32) -> split2 straight from frest.
// grid = (512, 2): RT=4, VS=2, each wave scans 32 tiles. (r10/r14-proven;
// VS=4, 2-deep pipe, and external-pool variants all regressed or tied.)
__global__ __launch_bounds__(256) void argmin5_fused(const float* __restrict__ frest,
                                                     const half_t* __restrict__ ehi,
                                                     const half_t* __restrict__ elo,
                                                     const float* __restrict__ nesqh,
                                                     u64_t* __restrict__ pk) {
    const int lane = threadIdx.x & 63;
    const int col  = lane & 15;
    const int quad = lane >> 4;
    const int row0 = blockIdx.x * 64;   // RT=4

    half8 a1[4], a2[4];
#pragma unroll
    for (int rt = 0; rt < 4; rt++) {
        int n = row0 + rt * 16 + col;               // row = (b*32+i)*32+j
        int b = n >> 10, i = (n >> 5) & 31, j = n & 31;
        const float* p = frest + ((((size_t)(b * CH + quad * 8)) * HH + i) * HH + j);
#pragma unroll
        for (int k = 0; k < 8; k++) {
            half_t h, l;
            split2(p[(size_t)k * (HH * HH)], &h, &l);   // c stride = 1024
            a1[rt][k] = h; a2[rt][k] = l;
        }
    }
    argmin_body<4, 32>(a1, a2, ehi, elo, nesqh, pk,
                       row0, (int)blockIdx.y * 128);
}

// ---------------------------------------------------------------------------
// bicubic weights, a=-0.75, half-pixel, edge clamp (matches ref _bicubic_mat)
__device__ inline void cubic_w(float xs, int pn, int* ix, float* w) {
    const float a = -0.75f;
    float xf = floorf(xs);
    int x0 = (int)xf;
    float t = xs - xf;
#pragma unroll
    for (int j = -1; j <= 2; j++) {
        float d = fabsf(t - (float)j);
        float ww;
        if (d < 1.0f)      ww = ((a + 2.0f) * d - (a + 3.0f)) * d * d + 1.0f;
        else if (d < 2.0f) ww = ((a * d - 5.0f * a) * d + 8.0f * a) * d - 4.0f * a;
        else               ww = 0.0f;
        int xi = x0 + j;
        xi = xi < 0 ? 0 : (xi > pn - 1 ? pn - 1 : xi);
        ix[j + 1] = xi;
        w[j + 1]  = ww;
    }
}

// Fused gather + bicubic upsample from packed keys (idx = low 32 bits).
// Thread mapping [b][c][Y][X], X minor -> coalesced hup writes; scattered
// emb gathers absorbed by L1/L2 (emb = 512 KB). (r5-verified layout.)
__global__ __launch_bounds__(256) void upsample_gather_kernel(const u64_t* __restrict__ pk,
                                                              const float* __restrict__ emb,
                                                              float* __restrict__ hu, int pn) {
    int tid = blockIdx.x * 256 + threadIdx.x;   // [b][c][Y][X]
    int X = tid & 31;
    int Y = (tid >> 5) & 31;
    int c = (tid >> 10) & 31;
    int b = tid >> 15;
    float scale = (float)pn / (float)HH;
    int iy[4], ix[4];
    float wy[4], wx[4];
    cubic_w(((float)Y + 0.5f) * scale - 0.5f, pn, iy, wy);
    cubic_w(((float)X + 0.5f) * scale - 0.5f, pn, ix, wx);
    const u64_t* ib = pk + b * pn * pn;
    float s = 0.f;
#pragma unroll
    for (int a = 0; a < 4; a++) {
        float rsum = 0.f;
#pragma unroll
        for (int b2 = 0; b2 < 4; b2++) {
            int idx = (int)(unsigned)(ib[iy[a] * pn + ix[b2]] & 0xFFFFFFFFull);
            rsum = fmaf(emb[(size_t)idx * CH + c], wx[b2], rsum);
        }
        s = fmaf(rsum, wy[a], s);
    }
    hu[tid] = s;
}

// ---------------------------------------------------------------------------
// Phi + residual: dst = src - (0.5*h + 0.5*(conv3x3(h)+bias))
// grid: b(32) x yt(8) x co-quarter(4) = 1024 blocks (4 blocks/CU);
// block 256 = tx(32) x ty(8); thread: 4 rows x col tx x 1 co (co = coq*8+ty).
// (r9/r10-proven shape. r11's 2-row variant blew VGPR to 180 — keep as-is.)
__global__ __launch_bounds__(256) void conv_phi_kernel(const float* __restrict__ hin,
                                                       const float* __restrict__ w,
                                                       const float* __restrict__ bias,
                                                       const float* __restrict__ src,
                                                       float* __restrict__ dst) {
    const int coq = blockIdx.x & 3;
    const int yt  = (blockIdx.x >> 2) & 7;
    const int b   = blockIdx.x >> 5;
    const int tx  = threadIdx.x & 31;
    const int ty  = threadIdx.x >> 5;     // 0..7
    const int y0  = yt * 4;

    __shared__ float wl[8 * 32 * 12];     // 12 KB
    __shared__ float til[16 * 6 * 34];    // 13.1 KB

    {
        const float* wsrc = w + (size_t)coq * 8 * CH * 9;
        for (int i = threadIdx.x; i < 8 * 32 * 12; i += 256) {
            int k = i % 12;
            wl[i] = (k < 9) ? wsrc[(i / 12) * 9 + k] : 0.f;
        }
    }

    const int co = coq * 8 + ty;
    float acc[4];
#pragma unroll
    for (int ry = 0; ry < 4; ry++) acc[ry] = bias[co];

    for (int cc = 0; cc < 2; cc++) {
        __syncthreads();
        // stage input: ci = cc*16 + 0..15, rows y0-1..y0+4, cols -1..32 (zero pad)
        for (int i = threadIdx.x; i < 16 * 6 * 34; i += 256) {
            int col = i % 34;
            int row = (i / 34) % 6;
            int cil = i / 204;
            int gy = y0 - 1 + row;
            int gx = col - 1;
            float vv = 0.f;
            if ((unsigned)gy < 32u && (unsigned)gx < 32u)
                vv = hin[(((size_t)(b * CH + cc * 16 + cil)) * HH + gy) * HH + gx];
            til[i] = vv;
        }
        __syncthreads();

        for (int cil = 0; cil < 16; cil++) {
            float in[6][3];
            const float* tp = &til[cil * 204];
#pragma unroll
            for (int rr2 = 0; rr2 < 6; rr2++)
#pragma unroll
                for (int dx = 0; dx < 3; dx++)
                    in[rr2][dx] = tp[rr2 * 34 + tx + dx];
            const float* wp = &wl[(ty * 32 + cc * 16 + cil) * 12];
            float4 wa = *(const float4*)wp;
            float4 wb = *(const float4*)(wp + 4);
            float  w8 = wp[8];
#pragma unroll
            for (int ry = 0; ry < 4; ry++) {
                float s = acc[ry];
                s = fmaf(in[ry + 0][0], wa.x, s);
                s = fmaf(in[ry + 0][1], wa.y, s);
                s = fmaf(in[ry + 0][2], wa.z, s);
                s = fmaf(in[ry + 1][0], wa.w, s);
                s = fmaf(in[ry + 1][1], wb.x, s);
                s = fmaf(in[ry + 1][2], wb.y, s);
                s = fmaf(in[ry + 2][0], wb.z, s);
                s = fmaf(in[ry + 2][1], wb.w, s);
                s = fmaf(in[ry + 2][2], w8,   s);
                acc[ry] = s;
            }
        }
    }

#pragma unroll
    for (int ry = 0; ry < 4; ry++) {
        size_t off = (((size_t)(b * CH + co)) * HH + (y0 + ry)) * HH + tx;
        float hc = hin[off];
        dst[off] = src[off] - (0.5f * hc + 0.5f * acc[ry]);
    }
}

// ---------------------------------------------------------------------------
// hits bincount over all scales' packed winners (multi-block, parallel)
__global__ __launch_bounds__(256) void bincount_kernel(const u64_t* __restrict__ pk,
                                                       float* __restrict__ hits, int n) {
    int i = blockIdx.x * 256 + threadIdx.x;
    if (i < n) {
        int idx = (int)(unsigned)(pk[i] & 0xFFFFFFFFull);
        atomicAdd(&hits[idx], 1.0f);
    }
}

// ---------------------------------------------------------------------------
// perplexity + loss finalize (single block; reads only the 4096-entry hist)
__global__ __launch_bounds__(256) void finalize_kernel(const float* __restrict__ hits,
                                                       const float* __restrict__ lacc,
                                                       float* __restrict__ outs) {
    __shared__ float sh[256];
    int t = threadIdx.x;
    // total = NROWS_TOTAL exactly (each row contributes one hit)
    const float tot = (float)NROWS_TOTAL;
    float ent = 0.f;
    for (int v = t; v < VV; v += 256) {
        float p = hits[v] / tot;
        ent += p * logf(p + 1e-10f);
    }
    sh[t] = ent;
    __syncthreads();
    for (int o = 128; o > 0; o >>= 1) {
        if (t < o) sh[t] += sh[t + o];
        __syncthreads();
    }
    if (t == 0) {
        // loss = SN*(1+BETA)*mean(f^2) = 7.5 * sumsq / 1048576  (f_hat stays 0)
        outs[0] = 7.5f * lacc[0] * (1.0f / (float)FELEMS);
        outs[1] = expf(-sh[0]);
    }
}

// ---------------------------------------------------------------------------
extern "C" void kernel_launch(void* const* d_in, const int* in_sizes, int n_in,
                              void* d_out, int out_size, void* d_ws, size_t ws_size,
                              hipStream_t stream) {
    const float* f   = (const float*)d_in[0];   // (32,32,32,32)
    const float* emb = (const float*)d_in[1];   // (4096,32)
    const float* phw = (const float*)d_in[2];   // (4,32,32,3,3)
    const float* phb = (const float*)d_in[3];   // (4,32)
    float* out = (float*)d_out;                 // f_hat (1048576) + loss + perplexity

    float* ws      = (float*)d_ws;
    float* hits    = ws;                              // [0, 4096)
    float* lacc    = ws + 8192;                       // [8192, 8448) padded
    u64_t* pkbase  = (u64_t*)(ws + 8448);             // 43680 u64 -> [8448, 95808)
    float* frest   = ws + 95808;                      // [95808, 1144384)
    half_t* zhi    = (half_t*)(ws + 1144384);         // 262144 halves = 131072 f
    half_t* zlo    = (half_t*)(ws + 1275456);         // ends 1406528
    float* nesqh   = ws + 1537600;                    // [1537600, 1541696)
    float* hup     = ws + 1541696;                    // [1541696, 2590272)
    half_t* ehi    = (half_t*)(ws + 2590272);         // 131072 halves = 65536 f
    half_t* elo    = (half_t*)(ws + 2655808);         // ends 2721344 (10.9 MB)

    // prep: emb split + nesqh + zero f_hat/hits/lacc + pk=+inf (no memset needed)
    prep_kernel<<<1024, 256, 0, stream>>>(emb, ehi, elo, nesqh, ws, pkbase, out);

    const int pns[6]   = {1, 2, 4, 8, 16, 32};
    const int sel[6]   = {0, 0, 1, 2, 3, 3};            // PHI_SEL
    const int pkoff[6] = {0, 32, 160, 672, 2720, 10912};

    for (int si = 0; si < 6; si++) {
        int pn = pns[si];
        int N = BS * pn * pn;
        u64_t* pk = pkbase + pkoff[si];
        const float* srcf = (si == 0) ? f : frest;      // frest not yet written at si=0

        if (si == 5) {
            argmin5_fused<<<dim3(512, 2), 256, 0, stream>>>(frest, ehi, elo, nesqh, pk);
        } else {
            if (si == 0)
                pool_big_kernel<true><<<N * CH, 256, 0, stream>>>(srcf, zhi, zlo, lacc, pn);
            else if (si == 1)
                pool_big_kernel<false><<<N * CH, 256, 0, stream>>>(srcf, zhi, zlo, lacc, pn);
            else if (si == 2)
                pool_wave_kernel<<<N * CH / 4, 256, 0, stream>>>(srcf, zhi, zlo);
            else
                pool_kernel<<<(N * CH) / 256, 256, 0, stream>>>(srcf, zhi, zlo, pn);

            if (si <= 2)        // N=32/128/512 -> grids 32/128/512 (r10 config)
                argmin_stage<1, 16><<<dim3(N / 16, 16), 256, 0, stream>>>(zhi, zlo, ehi, elo, nesqh, pk);
            else if (si == 3)   // N=2048 -> grid 1024 (r10 config)
                argmin_stage<1, 8><<<dim3(N / 16, 8), 256, 0, stream>>>(zhi, zlo, ehi, elo, nesqh, pk);
            else                // si=4, N=8192 -> grid 1024 (r10 config)
                argmin_stage<2, 4><<<dim3(N / 32, 4), 256, 0, stream>>>(zhi, zlo, ehi, elo, nesqh, pk);

            upsample_gather_kernel<<<FELEMS / 256, 256, 0, stream>>>(pk, emb, hup, pn);
            conv_phi_kernel<<<1024, 256, 0, stream>>>(
                hup, phw + (size_t)sel[si] * CH * CH * 9,
                phb + (size_t)sel[si] * CH, srcf, frest);
        }
    }

    bincount_kernel<<<(NROWS_TOTAL + 255) / 256, 256, 0, stream>>>(pkbase, hits, NROWS_TOTAL);
    finalize_kernel<<<1, 256, 0, stream>>>(hits, lacc, out + (out_size - 2));
}